// Round 2
// baseline (195.874 us; speedup 1.0000x reference)
//
#include <hip/hip_runtime.h>

#define B_ 4
#define T_ 2048
#define H_ 8
#define E_ 64
#define KDIM 512

typedef unsigned short ushort_t;
typedef __attribute__((ext_vector_type(4))) float f32x4;
typedef __attribute__((ext_vector_type(4))) int i32x4;
typedef __attribute__((ext_vector_type(8))) short s16x8;

// fold (1/64^0.25) * sqrt(log2(e)) into both Wq and Wk -> logits arrive pre-multiplied by log2(e)
#define QK_SCALE 0.42466043f

__device__ __forceinline__ ushort_t f2bf(float f) {   // RNE
  unsigned u = __builtin_bit_cast(unsigned, f);
  u += 0x7fffu + ((u >> 16) & 1u);
  return (ushort_t)(u >> 16);
}
__device__ __forceinline__ unsigned pk2(float a, float b) {  // RNE pack
  return (unsigned)f2bf(a) | ((unsigned)f2bf(b) << 16);
}
// truncating pack, single v_perm_b32: dst = {hi16(b), hi16(a)}
__device__ __forceinline__ unsigned pk2t(float a, float b) {
  return __builtin_amdgcn_perm(__builtin_bit_cast(unsigned, b),
                               __builtin_bit_cast(unsigned, a), 0x07060302u);
}
__device__ __forceinline__ float e2(float x) { return __builtin_amdgcn_exp2f(x); }
// async global->LDS, 16B per lane, LDS dest = wave-uniform base + lane*16
__device__ __forceinline__ void gl2lds16(const void* g, void* l) {
  __builtin_amdgcn_global_load_lds((const __attribute__((address_space(1))) unsigned*)g,
                                   (__attribute__((address_space(3))) unsigned*)l, 16, 0, 0);
}

// ---------------- weight prep: LDS-tiled transpose to [N][K] bf16, fold scales ------
__global__ void k_prep(const float* __restrict__ Wq, const float* __restrict__ Wk,
                       const float* __restrict__ Wv, ushort_t* __restrict__ wt) {
  __shared__ ushort_t tile[64][66];
  int z = blockIdx.z;
  const float* W = (z == 0) ? Wq : (z == 1 ? Wk : Wv);
  float scale = (z < 2) ? QK_SCALE : 1.0f;
  int k0 = blockIdx.y << 6, n0 = blockIdx.x << 6;
  int rr = threadIdx.x >> 6, cc = threadIdx.x & 63;
  for (int p = 0; p < 16; p++) {
    int kl = p * 4 + rr;
    tile[cc][kl] = f2bf(W[(size_t)(k0 + kl) * 512 + n0 + cc] * scale);
  }
  __syncthreads();
  int kp2 = threadIdx.x & 31, nr = threadIdx.x >> 5;
  unsigned* wt32 = (unsigned*)(wt + (size_t)z * 262144);
  for (int p = 0; p < 8; p++) {
    int nl = p * 8 + nr;
    unsigned val = (unsigned)tile[nl][kp2 * 2] | ((unsigned)tile[nl][kp2 * 2 + 1] << 16);
    wt32[(size_t)(n0 + nl) * 256 + (k0 >> 1) + kp2] = val;
  }
}

// ---------------- merge-weight softmax over heads: wgt[h][e] ------------------------
__global__ void k_wgt(const float* __restrict__ mw, float* __restrict__ wgt) {
  int e = threadIdx.x;  // 64 threads
  float w[8], wmax = -1e30f;
  for (int h = 0; h < 8; h++) { w[h] = mw[h * 64 + e]; wmax = fmaxf(wmax, w[h]); }
  float wsum = 0.f;
  for (int h = 0; h < 8; h++) { w[h] = __expf(w[h] - wmax); wsum += w[h]; }
  float inv = 1.f / wsum;
  for (int h = 0; h < 8; h++) wgt[h * 64 + e] = w[h] * inv;
}

// ---------------- activation fp32 -> bf16 pre-convert (streaming, RNE) --------------
__global__ void k_cvt(const float* __restrict__ obs, const float* __restrict__ st,
                      unsigned* __restrict__ xo, unsigned* __restrict__ xs) {
  int which = blockIdx.y;
  const float* src = which ? st : obs;
  unsigned* dst = which ? xs : xo;
  size_t idx = (size_t)blockIdx.x * 256 + threadIdx.x;  // 524288 threads, 8 elems each
  size_t base = idx * 8;
  float4 x0 = *(const float4*)(src + base);
  float4 x1 = *(const float4*)(src + base + 4);
  uint4 d;
  d.x = pk2(x0.x, x0.y);
  d.y = pk2(x0.z, x0.w);
  d.z = pk2(x1.x, x1.y);
  d.w = pk2(x1.z, x1.w);
  *(uint4*)(dst + idx * 4) = d;
}

// ---------------- QKV projection v10: v8 loop + LDS-bounce coalesced epilogue --------
// v9 post-mortem: (1) used global row m0 as t without &2047 -> wrong-batch writes,
// absmax 0.144; (2) ep[4][64][72] = 73.7 KB blew the union past 32 KB. v10: t0=m0&2047,
// and a 2-round epilogue (2 waves per round, 2 LDS tile slots = 18 KB) keeps the union
// at 32 KB (occupancy 3 blocks/CU unchanged). Stores are dwordx4, 8 full 128B lines per
// wave-instr (v8's 64 scalar 2B stores measured 4.8x HBM write amplification).
union ProjSmem {
  ushort_t As[2][128 * 64];   // 32 KB, K-loop staging
  ushort_t ep2[2][64][72];    // 18 KB, 2 epilogue tile slots ([72] pad: 144B rows, 16B-aligned)
};

__global__ __launch_bounds__(256, 3) void k_proj2(
    const ushort_t* __restrict__ xo, const ushort_t* __restrict__ xs,
    const ushort_t* __restrict__ wt,
    ushort_t* __restrict__ qo, ushort_t* __restrict__ ko, ushort_t* __restrict__ vto) {
  __shared__ __align__(16) ProjSmem sm;

  int id = blockIdx.x;              // 768
  int xcd = id & 7, nt = (id >> 3) & 3, ghi = id >> 5;
  int g = ghi * 8 + xcd;            // sibling group; 4 n-tiles share an XCD
  int which = g >> 6, mb = g & 63;
  int m0 = mb << 7, n0 = nt << 7;
  const ushort_t* X = (which == 0) ? xo : xs;
  const ushort_t* W = wt + which * 262144;

  int tid = threadIdx.x, wave = tid >> 6, lane = tid & 63;
  int l15 = lane & 15, quad = lane >> 4;
  int wm = wave & 1, wn = wave >> 1;

  f32x4 acc[4][4];
  for (int i = 0; i < 4; i++)
    for (int j = 0; j < 4; j++) acc[i][j] = (f32x4){0.f, 0.f, 0.f, 0.f};

  int arl = lane >> 3, ap = lane & 7;  // A stage: 8 rows/instr, 8 chunks(16B)/row

#define STAGEA(buf, k0)                                                            \
  do {                                                                             \
    for (int ii = 0; ii < 4; ii++) {                                               \
      int r = wave * 32 + ii * 8 + arl;                                            \
      gl2lds16(X + (size_t)(m0 + r) * KDIM + (k0) + ((ap ^ (r & 7)) << 3),         \
               &sm.As[buf][(wave * 32 + ii * 8) * 64]);                            \
    }                                                                              \
  } while (0)

  // B row pointers (advance by 64 per k-iter)
  const ushort_t* wb[4];
  for (int j = 0; j < 4; j++)
    wb[j] = W + (size_t)(n0 + wn * 64 + j * 16 + l15) * KDIM + quad * 8;

  STAGEA(0, 0);
  __builtin_amdgcn_s_waitcnt(0x0F70);  // vmcnt(0)
  __syncthreads();

  for (int kt = 0; kt < 8; kt++) {
    // 1) B register loads FIRST (their waitcnt keeps the A-prefetch in flight)
    s16x8 b[2][4];
    for (int kc = 0; kc < 2; kc++)
      for (int j = 0; j < 4; j++) b[kc][j] = *(const s16x8*)(wb[j] + kc * 32);
    for (int j = 0; j < 4; j++) wb[j] += 64;
    // 2) prefetch next A tile
    if (kt < 7) STAGEA((kt + 1) & 1, kt * 64 + 64);
    // 3) compute current tile (pure b128 LDS reads, no conversion)
    const ushort_t* asb = sm.As[kt & 1];
    for (int kc = 0; kc < 2; kc++) {
      s16x8 a[4];
      for (int i = 0; i < 4; i++) {
        int mr = wm * 64 + i * 16 + l15;
        int pc = (kc * 4 + quad) ^ (l15 & 7);
        a[i] = *(const s16x8*)&asb[mr * 64 + pc * 8];
      }
      if (which == 2) {
        for (int i = 0; i < 4; i++)
          for (int j = 0; j < 4; j++)
            acc[i][j] = __builtin_amdgcn_mfma_f32_16x16x32_bf16(b[kc][j], a[i], acc[i][j], 0, 0, 0);
      } else {
        for (int i = 0; i < 4; i++)
          for (int j = 0; j < 4; j++)
            acc[i][j] = __builtin_amdgcn_mfma_f32_16x16x32_bf16(a[i], b[kc][j], acc[i][j], 0, 0, 0);
      }
    }
    __builtin_amdgcn_s_waitcnt(0x0F70);  // vmcnt(0): next A landed
    __syncthreads();
  }
#undef STAGEA

  // ---- coalesced epilogue: per-wave LDS bounce -> full-line dwordx4 stores ----
  // Fragment layout: row dim = quad*4+r (tile index i for q/k, j for v), col dim = l15
  // (tile j for q/k, i for v). The output's contiguous dim equals the fragment col dim
  // in both orientations, so one LDS tile shape serves both. Two rounds x 2 waves so
  // only 2 tile slots (18 KB) are live and the union stays at 32 KB.
  {
    int t0m = m0 & 2047;                   // t-offset within batch (v9 bug: used m0 raw)
    int bb = m0 >> 11;                     // batch (128-row tile never crosses T boundary)
    int h = (n0 >> 6) + wn;                // head = 2*nt + wn
    int rrow = lane >> 3, chk = lane & 7;  // 8 rows / wave-instr, 8 x 16B chunks / row
    for (int round = 0; round < 2; round++) {
      __syncthreads();                     // drains lgkm: prev round's LDS reads done
      if ((wave >> 1) == round) {
        ushort_t (*ept)[72] = sm.ep2[wave & 1];
        for (int i = 0; i < 4; i++)
          for (int j = 0; j < 4; j++) {
            int ot = (which == 2) ? j : i;   // outer tile index (row dim)
            int it_ = (which == 2) ? i : j;  // inner tile index (col dim)
            for (int r = 0; r < 4; r++)
              ept[ot * 16 + quad * 4 + r][it_ * 16 + l15] = f2bf(acc[i][j][r]);
          }
        __builtin_amdgcn_s_waitcnt(0xC07F);  // lgkmcnt(0); tile is wave-private
        if (which != 2) {
          ushort_t* dst = (which == 0) ? qo : ko;
          // dst[((bb*H + h)*T + t)*64 + e], t = t0m + wm*64 + row, e = chk*8 + s
          size_t base = ((size_t)((bb * H_ + h) * T_ + t0m + wm * 64) << 6) + chk * 8;
          for (int itr = 0; itr < 8; itr++) {
            int row = itr * 8 + rrow;
            s16x8 v = *(const s16x8*)&ept[row][chk * 8];
            *(s16x8*)&dst[base + ((size_t)row << 6)] = v;
          }
        } else {
          // vto[((bb*H + h)*64 + e)*T + t], e = row, t = t0m + wm*64 + chk*8 + s
          size_t base = (size_t)((bb * H_ + h) << 6) * T_ + t0m + wm * 64 + chk * 8;
          for (int itr = 0; itr < 8; itr++) {
            int row = itr * 8 + rrow;
            s16x8 v = *(const s16x8*)&ept[row][chk * 8];
            *(s16x8*)&vto[base + (size_t)row * T_] = v;
          }
        }
      }
    }
  }
}

// ---------------- QKV projection v7 (fp32 fallback, proven) -------------------------
__global__ __launch_bounds__(256, 3) void k_proj(
    const float* __restrict__ obs, const float* __restrict__ st,
    const ushort_t* __restrict__ wt,
    ushort_t* __restrict__ qo, ushort_t* __restrict__ ko, ushort_t* __restrict__ vto) {
  __shared__ __align__(16) float As[2][128 * 32];   // 2 x 16 KB

  int id = blockIdx.x;              // 768
  int xcd = id & 7, nt = (id >> 3) & 3, ghi = id >> 5;
  int g = ghi * 8 + xcd;
  int which = g >> 6, mb = g & 63;
  int m0 = mb << 7, n0 = nt << 7;
  const float* X = (which == 0) ? obs : st;
  const ushort_t* W = wt + which * 262144;

  int tid = threadIdx.x, wave = tid >> 6, lane = tid & 63;
  int l15 = lane & 15, quad = lane >> 4;
  int wm = wave & 1, wn = wave >> 1;

  f32x4 acc[4][4];
  for (int i = 0; i < 4; i++)
    for (int j = 0; j < 4; j++) acc[i][j] = (f32x4){0.f, 0.f, 0.f, 0.f};

  int arl = lane >> 3, ap = lane & 7;

#define STAGEA(buf, k0)                                                           \
  do {                                                                            \
    for (int ii = 0; ii < 4; ii++) {                                              \
      int r = wave * 32 + ii * 8 + arl;                                           \
      gl2lds16(X + (size_t)(m0 + r) * KDIM + (k0) + ((ap ^ (r & 7)) << 2),        \
               &As[buf][(wave * 32 + ii * 8) * 32]);                              \
    }                                                                             \
  } while (0)

  const ushort_t* wb[4];
  for (int j = 0; j < 4; j++)
    wb[j] = W + (size_t)(n0 + wn * 64 + j * 16 + l15) * KDIM + quad * 8;

  STAGEA(0, 0);
  __builtin_amdgcn_s_waitcnt(0x0F70);
  __syncthreads();

  for (int kt = 0; kt < 16; kt++) {
    s16x8 b[4];
    for (int j = 0; j < 4; j++) { b[j] = *(const s16x8*)wb[j]; wb[j] += 32; }
    if (kt < 15) STAGEA((kt + 1) & 1, kt * 32 + 32);
    const float* asb = As[kt & 1];
    s16x8 a[4];
    for (int i = 0; i < 4; i++) {
      int mr = wm * 64 + i * 16 + l15;
      int s = mr & 7;
      const float* rowp = &asb[mr * 32];
      float4 x0 = *(const float4*)&rowp[(((quad << 1)) ^ s) << 2];
      float4 x1 = *(const float4*)&rowp[(((quad << 1) | 1) ^ s) << 2];
      i32x4 d;
      d[0] = (int)pk2(x0.x, x0.y);
      d[1] = (int)pk2(x0.z, x0.w);
      d[2] = (int)pk2(x1.x, x1.y);
      d[3] = (int)pk2(x1.z, x1.w);
      a[i] = __builtin_bit_cast(s16x8, d);
    }
    if (which == 2) {
      for (int i = 0; i < 4; i++)
        for (int j = 0; j < 4; j++)
          acc[i][j] = __builtin_amdgcn_mfma_f32_16x16x32_bf16(b[j], a[i], acc[i][j], 0, 0, 0);
    } else {
      for (int i = 0; i < 4; i++)
        for (int j = 0; j < 4; j++)
          acc[i][j] = __builtin_amdgcn_mfma_f32_16x16x32_bf16(a[i], b[j], acc[i][j], 0, 0, 0);
    }
    __builtin_amdgcn_s_waitcnt(0x0F70);
    __syncthreads();
  }
#undef STAGEA

  if (which != 2) {
    ushort_t* dst = (which == 0) ? qo : ko;
    for (int i = 0; i < 4; i++) {
      int grow = m0 + wm * 64 + i * 16 + quad * 4;
      for (int j = 0; j < 4; j++) {
        int gcol = n0 + wn * 64 + j * 16 + l15;
        int h = gcol >> 6, e = gcol & 63;
        for (int r = 0; r < 4; r++) {
          int row = grow + r;
          int bb = row >> 11, t = row & 2047;
          int bh = bb * H_ + h;
          dst[(((size_t)bh * T_ + t) << 6) + e] = f2bf(acc[i][j][r]);
        }
      }
    }
  } else {
    for (int i = 0; i < 4; i++) {
      int row = m0 + wm * 64 + i * 16 + l15;
      int bb = row >> 11, t = row & 2047;
      for (int j = 0; j < 4; j++) {
        for (int r = 0; r < 4; r++) {
          int gcol = n0 + wn * 64 + j * 16 + quad * 4 + r;
          int h = gcol >> 6, e = gcol & 63;
          int bh = bb * H_ + h;
          vto[((size_t)(bh << 6) + e) * T_ + t] = f2bf(acc[i][j][r]);
        }
      }
    }
  }
}

// ---------------- flash attention v6: 64-key tiles, 32 KB LDS, coalesced epilogue ----
union AttnSmem {
  struct { ushort_t ks[2][64 * 64]; ushort_t vs[2][64 * 64]; } st;  // 32 KB
  struct { float ows[64 * 65]; float linv[64]; } ep;                // 16.9 KB
};

__global__ __launch_bounds__(256, 4) void k_attn(
    const ushort_t* __restrict__ q, const ushort_t* __restrict__ k,
    const ushort_t* __restrict__ vt, const float* __restrict__ wgt,
    float* __restrict__ out) {
  __shared__ __align__(16) AttnSmem sm;

  int id = blockIdx.x;      // 512; bh fastest -> 4 heads/XCD (K+V L2-resident)
  int bh = id & 31, qt = id >> 5;
  int tid = threadIdx.x, wave = tid >> 6, lane = tid & 63;
  int l15 = lane & 15, quad = lane >> 4;

  s16x8 qf[2][2];
  for (int qs = 0; qs < 2; qs++) {
    const ushort_t* qp =
        q + (((size_t)bh * T_ + qt * 128 + wave * 32 + qs * 16 + l15) << 6) + quad * 8;
    qf[qs][0] = *(const s16x8*)qp;
    qf[qs][1] = *(const s16x8*)(qp + 32);
  }
  int hh = bh & 7;
  float wgl = wgt[hh * 64 + lane];

  f32x4 o[2][4];
  for (int qs = 0; qs < 2; qs++)
    for (int j = 0; j < 4; j++) o[qs][j] = (f32x4){0.f, 0.f, 0.f, 0.f};
  f32x4 lacc[2] = {(f32x4){0.f, 0.f, 0.f, 0.f}, (f32x4){0.f, 0.f, 0.f, 0.f}};
  const s16x8 ones = {16256, 16256, 16256, 16256, 16256, 16256, 16256, 16256};  // bf16 1.0

  int srl = lane >> 3, sp = lane & 7;
  const ushort_t* kbase = k + ((size_t)bh * T_ << 6);
  const ushort_t* vbase = vt + ((size_t)bh << 6) * T_;
  const ushort_t* kptr[2];
  const ushort_t* vptr[2];
  for (int ii = 0; ii < 2; ii++) {
    int r = wave * 16 + ii * 8 + srl;
    int gkey = (r & 32) + (((r >> 2) & 3) << 3) + (((r >> 4) & 1) << 2) + (r & 3);
    kptr[ii] = kbase + ((size_t)gkey << 6) + ((sp ^ (r & 7)) << 3);
    int e = r;
    vptr[ii] = vbase + (size_t)e * T_ + ((sp ^ (e & 7)) << 3);
  }

#define STAGE(buf)                                                         \
  do {                                                                     \
    for (int ii = 0; ii < 2; ii++) {                                       \
      gl2lds16(kptr[ii], &sm.st.ks[buf][(wave * 16 + ii * 8) * 64]);       \
      gl2lds16(vptr[ii], &sm.st.vs[buf][(wave * 16 + ii * 8) * 64]);       \
      kptr[ii] += 64 * 64;                                                 \
      vptr[ii] += 64;                                                      \
    }                                                                      \
  } while (0)

  STAGE(0);
  for (int kt = 0; kt < 32; kt++) {
    __builtin_amdgcn_s_waitcnt(0x0F70);  // vmcnt(0): prev staging landed
    __syncthreads();
    if (kt < 31) STAGE((kt + 1) & 1);
    const ushort_t* ksb = sm.st.ks[kt & 1];
    const ushort_t* vsb = sm.st.vs[kt & 1];

    s16x8 bfr[2][2];
    for (int c = 0; c < 2; c++) {
      f32x4 s0[2], s1[2];
      for (int qs = 0; qs < 2; qs++) {
        s0[qs] = (f32x4){0.f, 0.f, 0.f, 0.f};
        s1[qs] = (f32x4){0.f, 0.f, 0.f, 0.f};
      }
      for (int kc = 0; kc < 2; kc++) {
        int pc = (kc * 4 + quad) ^ (l15 & 7);
        s16x8 k0f = *(const s16x8*)&ksb[(c * 32 + l15) * 64 + pc * 8];
        s16x8 k1f = *(const s16x8*)&ksb[(c * 32 + 16 + l15) * 64 + pc * 8];
        for (int qs = 0; qs < 2; qs++) {
          s0[qs] = __builtin_amdgcn_mfma_f32_16x16x32_bf16(k0f, qf[qs][kc], s0[qs], 0, 0, 0);
          s1[qs] = __builtin_amdgcn_mfma_f32_16x16x32_bf16(k1f, qf[qs][kc], s1[qs], 0, 0, 0);
        }
      }
      for (int qs = 0; qs < 2; qs++) {
        i32x4 d;
        d[0] = (int)pk2t(e2(s0[qs][0]), e2(s0[qs][1]));
        d[1] = (int)pk2t(e2(s0[qs][2]), e2(s0[qs][3]));
        d[2] = (int)pk2t(e2(s1[qs][0]), e2(s1[qs][1]));
        d[3] = (int)pk2t(e2(s1[qs][2]), e2(s1[qs][3]));
        bfr[qs][c] = __builtin_bit_cast(s16x8, d);
      }
    }

    for (int c = 0; c < 2; c++) {
      lacc[0] = __builtin_amdgcn_mfma_f32_16x16x32_bf16(ones, bfr[0][c], lacc[0], 0, 0, 0);
      lacc[1] = __builtin_amdgcn_mfma_f32_16x16x32_bf16(ones, bfr[1][c], lacc[1], 0, 0, 0);
      for (int et = 0; et < 4; et++) {
        int pc = (c * 4 + quad) ^ (l15 & 7);
        s16x8 vf = *(const s16x8*)&vsb[(et * 16 + l15) * 64 + pc * 8];
        o[0][et] = __builtin_amdgcn_mfma_f32_16x16x32_bf16(vf, bfr[0][c], o[0][et], 0, 0, 0);
        o[1][et] = __builtin_amdgcn_mfma_f32_16x16x32_bf16(vf, bfr[1][c], o[1][et], 0, 0, 0);
      }
    }
  }
#undef STAGE

  int bb = bh >> 3;
  for (int half = 0; half < 2; half++) {
    __syncthreads();
    if ((wave >> 1) == half) {
      int tl = (wave & 1) * 32;
      for (int qs = 0; qs < 2; qs++) {
        int row = tl + qs * 16 + l15;
        if (quad == 0) sm.ep.linv[row] = 1.f / lacc[qs][0];
        for (int et = 0; et < 4; et++)
          for (int r = 0; r < 4; r++)
            sm.ep.ows[row * 65 + et * 16 + quad * 4 + r] = o[qs][et][r];
      }
    }
    __syncthreads();
    for (int i = 0; i < 16; i++) {
      int row = wave * 16 + i;
      int gt = qt * 128 + half * 64 + row;
      float val = sm.ep.ows[row * 65 + lane] * sm.ep.linv[row] * wgl;
      atomicAdd(&out[(((size_t)bb * T_ + gt) << 6) + lane], val);
    }
  }
}

extern "C" void kernel_launch(void* const* d_in, const int* in_sizes, int n_in,
                              void* d_out, int out_size, void* d_ws, size_t ws_size,
                              hipStream_t stream) {
  const float* obs = (const float*)d_in[0];
  const float* st  = (const float*)d_in[1];
  const float* Wq  = (const float*)d_in[2];
  const float* Wk  = (const float*)d_in[3];
  const float* Wv  = (const float*)d_in[4];
  const float* mw  = (const float*)d_in[5];

  const size_t WS_NEEDED = 27262976;   // proven 26 MB layout
  const size_t WS_BIG    = 44040192;   // +16 MB bf16 activations
  char* ws = (char*)d_ws;
  ushort_t* wt  = (ushort_t*)ws;                     // 1.5 MB
  float*    wgt = (float*)(ws + 1572864u);           // 2 KB
  ushort_t* qo  = (ushort_t*)(ws + 2097152u);        // [B,H,T,E] bf16, 8 MB
  ushort_t* ko  = (ushort_t*)(ws + 10485760u);       // [B,H,T,E] bf16, 8 MB
  ushort_t* vto = (ushort_t*)(ws + 18874368u);       // [B,H,E,T] bf16, 8 MB
  ushort_t* xo  = (ushort_t*)(ws + 27262976u);       // obs bf16, 8 MB
  ushort_t* xs  = (ushort_t*)(ws + 35651584u);       // st  bf16, 8 MB
  float*    out = (float*)d_out;

  hipMemsetAsync(d_out, 0, (size_t)out_size * sizeof(float), stream);
  if (ws_size < WS_NEEDED) return;

  hipLaunchKernelGGL(k_prep, dim3(8, 8, 3), dim3(256), 0, stream, Wq, Wk, Wv, wt);
  hipLaunchKernelGGL(k_wgt,  dim3(1),       dim3(64),  0, stream, mw, wgt);
  if (ws_size >= WS_BIG) {
    hipLaunchKernelGGL(k_cvt,   dim3(2048, 2), dim3(256), 0, stream, obs, st,
                       (unsigned*)xo, (unsigned*)xs);
    hipLaunchKernelGGL(k_proj2, dim3(768),     dim3(256), 0, stream, xo, xs, wt, qo, ko, vto);
  } else {
    hipLaunchKernelGGL(k_proj,  dim3(768),     dim3(256), 0, stream, obs, st, wt, qo, ko, vto);
  }
  hipLaunchKernelGGL(k_attn, dim3(512), dim3(256), 0, stream, qo, ko, vto, wgt, out);
}

// Round 3
// 186.309 us; speedup vs baseline: 1.0513x; 1.0513x over previous
//
#include <hip/hip_runtime.h>

#define B_ 4
#define T_ 2048
#define H_ 8
#define E_ 64
#define KDIM 512

typedef unsigned short ushort_t;
typedef __attribute__((ext_vector_type(4))) float f32x4;
typedef __attribute__((ext_vector_type(4))) int i32x4;
typedef __attribute__((ext_vector_type(8))) short s16x8;

// fold (1/64^0.25) * sqrt(log2(e)) into both Wq and Wk -> logits arrive pre-multiplied by log2(e)
#define QK_SCALE 0.42466043f

__device__ __forceinline__ ushort_t f2bf(float f) {   // RNE
  unsigned u = __builtin_bit_cast(unsigned, f);
  u += 0x7fffu + ((u >> 16) & 1u);
  return (ushort_t)(u >> 16);
}
__device__ __forceinline__ unsigned pk2(float a, float b) {  // RNE pack
  return (unsigned)f2bf(a) | ((unsigned)f2bf(b) << 16);
}
// truncating pack, single v_perm_b32: dst = {hi16(b), hi16(a)}
__device__ __forceinline__ unsigned pk2t(float a, float b) {
  return __builtin_amdgcn_perm(__builtin_bit_cast(unsigned, b),
                               __builtin_bit_cast(unsigned, a), 0x07060302u);
}
__device__ __forceinline__ float e2(float x) { return __builtin_amdgcn_exp2f(x); }
// async global->LDS, 16B per lane, LDS dest = wave-uniform base + lane*16
__device__ __forceinline__ void gl2lds16(const void* g, void* l) {
  __builtin_amdgcn_global_load_lds((const __attribute__((address_space(1))) unsigned*)g,
                                   (__attribute__((address_space(3))) unsigned*)l, 16, 0, 0);
}

// ---------------- weight prep: LDS-tiled transpose to [N][K] bf16, fold scales ------
__global__ void k_prep(const float* __restrict__ Wq, const float* __restrict__ Wk,
                       const float* __restrict__ Wv, ushort_t* __restrict__ wt) {
  __shared__ ushort_t tile[64][66];
  int z = blockIdx.z;
  const float* W = (z == 0) ? Wq : (z == 1 ? Wk : Wv);
  float scale = (z < 2) ? QK_SCALE : 1.0f;
  int k0 = blockIdx.y << 6, n0 = blockIdx.x << 6;
  int rr = threadIdx.x >> 6, cc = threadIdx.x & 63;
  for (int p = 0; p < 16; p++) {
    int kl = p * 4 + rr;
    tile[cc][kl] = f2bf(W[(size_t)(k0 + kl) * 512 + n0 + cc] * scale);
  }
  __syncthreads();
  int kp2 = threadIdx.x & 31, nr = threadIdx.x >> 5;
  unsigned* wt32 = (unsigned*)(wt + (size_t)z * 262144);
  for (int p = 0; p < 8; p++) {
    int nl = p * 8 + nr;
    unsigned val = (unsigned)tile[nl][kp2 * 2] | ((unsigned)tile[nl][kp2 * 2 + 1] << 16);
    wt32[(size_t)(n0 + nl) * 256 + (k0 >> 1) + kp2] = val;
  }
}

// ---------------- merge-weight softmax over heads: wgt[h][e] ------------------------
__global__ void k_wgt(const float* __restrict__ mw, float* __restrict__ wgt) {
  int e = threadIdx.x;  // 64 threads
  float w[8], wmax = -1e30f;
  for (int h = 0; h < 8; h++) { w[h] = mw[h * 64 + e]; wmax = fmaxf(wmax, w[h]); }
  float wsum = 0.f;
  for (int h = 0; h < 8; h++) { w[h] = __expf(w[h] - wmax); wsum += w[h]; }
  float inv = 1.f / wsum;
  for (int h = 0; h < 8; h++) wgt[h * 64 + e] = w[h] * inv;
}

// ---------------- activation fp32 -> bf16 pre-convert (streaming, RNE) --------------
__global__ void k_cvt(const float* __restrict__ obs, const float* __restrict__ st,
                      unsigned* __restrict__ xo, unsigned* __restrict__ xs) {
  int which = blockIdx.y;
  const float* src = which ? st : obs;
  unsigned* dst = which ? xs : xo;
  size_t idx = (size_t)blockIdx.x * 256 + threadIdx.x;  // 524288 threads, 8 elems each
  size_t base = idx * 8;
  float4 x0 = *(const float4*)(src + base);
  float4 x1 = *(const float4*)(src + base + 4);
  uint4 d;
  d.x = pk2(x0.x, x0.y);
  d.y = pk2(x0.z, x0.w);
  d.z = pk2(x1.x, x1.y);
  d.w = pk2(x1.z, x1.w);
  *(uint4*)(dst + idx * 4) = d;
}

// ---------------- QKV projection v11: 3-deep staging, counted vmcnt, raw s_barrier --
// v10 post-mortem: full-line stores did NOT reduce WRITE_SIZE or dur -> writes are not
// the constraint; epilogue reverted to v8 scalar stores. The binding constraint is the
// 2-phase drain-0 schedule (stage -> vmcnt(0) -> __syncthreads each iter; m233: that
// overhead is ~72% of time). v11: As[3] rotation, tile kt+2 staged at iter kt, ONE
// counted wait vmcnt(4) pre-compute (retires B[kt]+tile kt+1, keeps tile kt+2 in
// flight), raw s_barrier (no implicit vmcnt(0) drain).
__global__ __launch_bounds__(256, 3) void k_proj2(
    const ushort_t* __restrict__ xo, const ushort_t* __restrict__ xs,
    const ushort_t* __restrict__ wt,
    ushort_t* __restrict__ qo, ushort_t* __restrict__ ko, ushort_t* __restrict__ vto) {
  __shared__ __align__(16) ushort_t As[3][128 * 64];   // 48 KB, 3 blocks/CU

  int id = blockIdx.x;              // 768
  int xcd = id & 7, nt = (id >> 3) & 3, ghi = id >> 5;
  int g = ghi * 8 + xcd;            // sibling group; 4 n-tiles share an XCD
  int which = g >> 6, mb = g & 63;
  int m0 = mb << 7, n0 = nt << 7;
  const ushort_t* X = (which == 0) ? xo : xs;
  const ushort_t* W = wt + which * 262144;

  int tid = threadIdx.x, wave = tid >> 6, lane = tid & 63;
  int l15 = lane & 15, quad = lane >> 4;
  int wm = wave & 1, wn = wave >> 1;

  f32x4 acc[4][4];
  for (int i = 0; i < 4; i++)
    for (int j = 0; j < 4; j++) acc[i][j] = (f32x4){0.f, 0.f, 0.f, 0.f};

  int arl = lane >> 3, ap = lane & 7;  // A stage: 8 rows/instr, 8 chunks(16B)/row

#define STAGEA(buf, k0)                                                            \
  do {                                                                             \
    for (int ii = 0; ii < 4; ii++) {                                               \
      int r = wave * 32 + ii * 8 + arl;                                            \
      gl2lds16(X + (size_t)(m0 + r) * KDIM + (k0) + ((ap ^ (r & 7)) << 3),         \
               &As[buf][(wave * 32 + ii * 8) * 64]);                               \
    }                                                                              \
  } while (0)

  // B row pointers (advance by 64 per k-iter)
  const ushort_t* wb[4];
  for (int j = 0; j < 4; j++)
    wb[j] = W + (size_t)(n0 + wn * 64 + j * 16 + l15) * KDIM + quad * 8;

  STAGEA(0, 0);                        // tile 0 (4 ops/wave)
  STAGEA(1, 64);                       // tile 1 (4 ops/wave)
  __builtin_amdgcn_s_waitcnt(0x0F74);  // vmcnt(4): tile0 landed, tile1 in flight
  __builtin_amdgcn_s_barrier();
  __builtin_amdgcn_sched_barrier(0);

#pragma unroll
  for (int kt = 0; kt < 8; kt++) {
    // 1) B[kt] register loads FIRST (8 ops; issued before the newest stage so the
    //    pre-compute wait retires B without draining the in-flight stage)
    s16x8 b[2][4];
    for (int kc = 0; kc < 2; kc++)
      for (int j = 0; j < 4; j++) b[kc][j] = *(const s16x8*)(wb[j] + kc * 32);
    for (int j = 0; j < 4; j++) wb[j] += 64;
    // 2) stage tile kt+2 (4 ops) into buffer (kt+2)%3 — its readers ran in iter kt-1,
    //    separated by the end-of-(kt-1) barrier
    if (kt < 6) STAGEA((kt + 2) % 3, (kt + 2) * 64);
    // 3) counted wait: retire B[kt] + tile kt+1 (staged one full iter ago); keep the
    //    4 newest (tile kt+2) in flight across compute AND the barrier
    if (kt < 6) __builtin_amdgcn_s_waitcnt(0x0F74);   // vmcnt(4)
    else        __builtin_amdgcn_s_waitcnt(0x0F70);   // tail: vmcnt(0)
    __builtin_amdgcn_sched_barrier(0);
    // 4) compute current tile (pure b128 LDS reads, no conversion)
    const ushort_t* asb = As[kt % 3];
    for (int kc = 0; kc < 2; kc++) {
      s16x8 a[4];
      for (int i = 0; i < 4; i++) {
        int mr = wm * 64 + i * 16 + l15;
        int pc = (kc * 4 + quad) ^ (l15 & 7);
        a[i] = *(const s16x8*)&asb[mr * 64 + pc * 8];
      }
      if (which == 2) {
        for (int i = 0; i < 4; i++)
          for (int j = 0; j < 4; j++)
            acc[i][j] = __builtin_amdgcn_mfma_f32_16x16x32_bf16(b[kc][j], a[i], acc[i][j], 0, 0, 0);
      } else {
        for (int i = 0; i < 4; i++)
          for (int j = 0; j < 4; j++)
            acc[i][j] = __builtin_amdgcn_mfma_f32_16x16x32_bf16(a[i], b[kc][j], acc[i][j], 0, 0, 0);
      }
    }
    if (kt < 7) {
      __builtin_amdgcn_s_barrier();    // raw barrier: no implicit vmcnt(0) drain
      __builtin_amdgcn_sched_barrier(0);
    }
  }
#undef STAGEA

  // ---- v8 epilogue (proven; writes are not the binding constraint) ----
  if (which != 2) {
    ushort_t* dst = (which == 0) ? qo : ko;
    for (int i = 0; i < 4; i++) {
      int grow = m0 + wm * 64 + i * 16 + quad * 4;
      for (int j = 0; j < 4; j++) {
        int gcol = n0 + wn * 64 + j * 16 + l15;
        int h = gcol >> 6, e = gcol & 63;
        for (int r = 0; r < 4; r++) {
          int row = grow + r;
          int bb = row >> 11, t = row & 2047;
          int bh = bb * H_ + h;
          dst[(((size_t)bh * T_ + t) << 6) + e] = f2bf(acc[i][j][r]);
        }
      }
    }
  } else {
    for (int i = 0; i < 4; i++) {
      int row = m0 + wm * 64 + i * 16 + l15;
      int bb = row >> 11, t = row & 2047;
      for (int j = 0; j < 4; j++) {
        for (int r = 0; r < 4; r++) {
          int gcol = n0 + wn * 64 + j * 16 + quad * 4 + r;
          int h = gcol >> 6, e = gcol & 63;
          int bh = bb * H_ + h;
          vto[((size_t)(bh << 6) + e) * T_ + t] = f2bf(acc[i][j][r]);
        }
      }
    }
  }
}

// ---------------- QKV projection v7 (fp32 fallback, proven) -------------------------
__global__ __launch_bounds__(256, 3) void k_proj(
    const float* __restrict__ obs, const float* __restrict__ st,
    const ushort_t* __restrict__ wt,
    ushort_t* __restrict__ qo, ushort_t* __restrict__ ko, ushort_t* __restrict__ vto) {
  __shared__ __align__(16) float As[2][128 * 32];   // 2 x 16 KB

  int id = blockIdx.x;              // 768
  int xcd = id & 7, nt = (id >> 3) & 3, ghi = id >> 5;
  int g = ghi * 8 + xcd;
  int which = g >> 6, mb = g & 63;
  int m0 = mb << 7, n0 = nt << 7;
  const float* X = (which == 0) ? obs : st;
  const ushort_t* W = wt + which * 262144;

  int tid = threadIdx.x, wave = tid >> 6, lane = tid & 63;
  int l15 = lane & 15, quad = lane >> 4;
  int wm = wave & 1, wn = wave >> 1;

  f32x4 acc[4][4];
  for (int i = 0; i < 4; i++)
    for (int j = 0; j < 4; j++) acc[i][j] = (f32x4){0.f, 0.f, 0.f, 0.f};

  int arl = lane >> 3, ap = lane & 7;

#define STAGEA(buf, k0)                                                           \
  do {                                                                            \
    for (int ii = 0; ii < 4; ii++) {                                              \
      int r = wave * 32 + ii * 8 + arl;                                           \
      gl2lds16(X + (size_t)(m0 + r) * KDIM + (k0) + ((ap ^ (r & 7)) << 2),        \
               &As[buf][(wave * 32 + ii * 8) * 32]);                              \
    }                                                                             \
  } while (0)

  const ushort_t* wb[4];
  for (int j = 0; j < 4; j++)
    wb[j] = W + (size_t)(n0 + wn * 64 + j * 16 + l15) * KDIM + quad * 8;

  STAGEA(0, 0);
  __builtin_amdgcn_s_waitcnt(0x0F70);
  __syncthreads();

  for (int kt = 0; kt < 16; kt++) {
    s16x8 b[4];
    for (int j = 0; j < 4; j++) { b[j] = *(const s16x8*)wb[j]; wb[j] += 32; }
    if (kt < 15) STAGEA((kt + 1) & 1, kt * 32 + 32);
    const float* asb = As[kt & 1];
    s16x8 a[4];
    for (int i = 0; i < 4; i++) {
      int mr = wm * 64 + i * 16 + l15;
      int s = mr & 7;
      const float* rowp = &asb[mr * 32];
      float4 x0 = *(const float4*)&rowp[(((quad << 1)) ^ s) << 2];
      float4 x1 = *(const float4*)&rowp[(((quad << 1) | 1) ^ s) << 2];
      i32x4 d;
      d[0] = (int)pk2(x0.x, x0.y);
      d[1] = (int)pk2(x0.z, x0.w);
      d[2] = (int)pk2(x1.x, x1.y);
      d[3] = (int)pk2(x1.z, x1.w);
      a[i] = __builtin_bit_cast(s16x8, d);
    }
    if (which == 2) {
      for (int i = 0; i < 4; i++)
        for (int j = 0; j < 4; j++)
          acc[i][j] = __builtin_amdgcn_mfma_f32_16x16x32_bf16(b[j], a[i], acc[i][j], 0, 0, 0);
    } else {
      for (int i = 0; i < 4; i++)
        for (int j = 0; j < 4; j++)
          acc[i][j] = __builtin_amdgcn_mfma_f32_16x16x32_bf16(a[i], b[j], acc[i][j], 0, 0, 0);
    }
    __builtin_amdgcn_s_waitcnt(0x0F70);
    __syncthreads();
  }
#undef STAGEA

  if (which != 2) {
    ushort_t* dst = (which == 0) ? qo : ko;
    for (int i = 0; i < 4; i++) {
      int grow = m0 + wm * 64 + i * 16 + quad * 4;
      for (int j = 0; j < 4; j++) {
        int gcol = n0 + wn * 64 + j * 16 + l15;
        int h = gcol >> 6, e = gcol & 63;
        for (int r = 0; r < 4; r++) {
          int row = grow + r;
          int bb = row >> 11, t = row & 2047;
          int bh = bb * H_ + h;
          dst[(((size_t)bh * T_ + t) << 6) + e] = f2bf(acc[i][j][r]);
        }
      }
    }
  } else {
    for (int i = 0; i < 4; i++) {
      int row = m0 + wm * 64 + i * 16 + l15;
      int bb = row >> 11, t = row & 2047;
      for (int j = 0; j < 4; j++) {
        for (int r = 0; r < 4; r++) {
          int gcol = n0 + wn * 64 + j * 16 + quad * 4 + r;
          int h = gcol >> 6, e = gcol & 63;
          int bh = bb * H_ + h;
          vto[((size_t)(bh << 6) + e) * T_ + t] = f2bf(acc[i][j][r]);
        }
      }
    }
  }
}

// ---------------- flash attention v7: 3-deep staging, counted vmcnt, raw s_barrier ---
// Same schedule surgery as k_proj2 v11: tile kt+2 staged pre-compute, post-compute
// vmcnt(4) retires only tile kt+1 (one full compute phase to land), raw s_barrier.
// 48 KB LDS — only 2 blocks/CU resident anyway (512 blocks / 256 CUs).
union AttnSmem {
  struct { ushort_t ks[3][64 * 64]; ushort_t vs[3][64 * 64]; } st;  // 48 KB
  struct { float ows[64 * 65]; float linv[64]; } ep;                // 16.9 KB
};

__global__ __launch_bounds__(256, 2) void k_attn(
    const ushort_t* __restrict__ q, const ushort_t* __restrict__ k,
    const ushort_t* __restrict__ vt, const float* __restrict__ wgt,
    float* __restrict__ out) {
  __shared__ __align__(16) AttnSmem sm;

  int id = blockIdx.x;      // 512; bh fastest -> 4 heads/XCD (K+V L2-resident)
  int bh = id & 31, qt = id >> 5;
  int tid = threadIdx.x, wave = tid >> 6, lane = tid & 63;
  int l15 = lane & 15, quad = lane >> 4;

  s16x8 qf[2][2];
  for (int qs = 0; qs < 2; qs++) {
    const ushort_t* qp =
        q + (((size_t)bh * T_ + qt * 128 + wave * 32 + qs * 16 + l15) << 6) + quad * 8;
    qf[qs][0] = *(const s16x8*)qp;
    qf[qs][1] = *(const s16x8*)(qp + 32);
  }
  int hh = bh & 7;
  float wgl = wgt[hh * 64 + lane];

  f32x4 o[2][4];
  for (int qs = 0; qs < 2; qs++)
    for (int j = 0; j < 4; j++) o[qs][j] = (f32x4){0.f, 0.f, 0.f, 0.f};
  f32x4 lacc[2] = {(f32x4){0.f, 0.f, 0.f, 0.f}, (f32x4){0.f, 0.f, 0.f, 0.f}};
  const s16x8 ones = {16256, 16256, 16256, 16256, 16256, 16256, 16256, 16256};  // bf16 1.0

  int srl = lane >> 3, sp = lane & 7;
  const ushort_t* kbase = k + ((size_t)bh * T_ << 6);
  const ushort_t* vbase = vt + ((size_t)bh << 6) * T_;
  const ushort_t* kptr[2];
  const ushort_t* vptr[2];
  for (int ii = 0; ii < 2; ii++) {
    int r = wave * 16 + ii * 8 + srl;
    int gkey = (r & 32) + (((r >> 2) & 3) << 3) + (((r >> 4) & 1) << 2) + (r & 3);
    kptr[ii] = kbase + ((size_t)gkey << 6) + ((sp ^ (r & 7)) << 3);
    int e = r;
    vptr[ii] = vbase + (size_t)e * T_ + ((sp ^ (e & 7)) << 3);
  }

#define STAGE(buf)                                                         \
  do {                                                                     \
    for (int ii = 0; ii < 2; ii++) {                                       \
      gl2lds16(kptr[ii], &sm.st.ks[buf][(wave * 16 + ii * 8) * 64]);       \
      gl2lds16(vptr[ii], &sm.st.vs[buf][(wave * 16 + ii * 8) * 64]);       \
      kptr[ii] += 64 * 64;                                                 \
      vptr[ii] += 64;                                                      \
    }                                                                      \
  } while (0)

  STAGE(0);                            // tile 0 (4 ops/wave)
  STAGE(1);                            // tile 1 (4 ops/wave)
  __builtin_amdgcn_s_waitcnt(0x0F74);  // vmcnt(4): tile0 landed (Q/wgt retire first)
  __builtin_amdgcn_s_barrier();
  __builtin_amdgcn_sched_barrier(0);

  int cur = 0, pre = 2;                // read buffer, stage buffer (= (kt+2)%3)
  for (int kt = 0; kt < 32; kt++) {
    if (kt < 30) STAGE(pre);           // tile kt+2; its readers ran in iter kt-1
    const ushort_t* ksb = &sm.st.ks[0][0] + cur * 4096;
    const ushort_t* vsb = &sm.st.vs[0][0] + cur * 4096;

    s16x8 bfr[2][2];
    for (int c = 0; c < 2; c++) {
      f32x4 s0[2], s1[2];
      for (int qs = 0; qs < 2; qs++) {
        s0[qs] = (f32x4){0.f, 0.f, 0.f, 0.f};
        s1[qs] = (f32x4){0.f, 0.f, 0.f, 0.f};
      }
      for (int kc = 0; kc < 2; kc++) {
        int pc = (kc * 4 + quad) ^ (l15 & 7);
        s16x8 k0f = *(const s16x8*)&ksb[(c * 32 + l15) * 64 + pc * 8];
        s16x8 k1f = *(const s16x8*)&ksb[(c * 32 + 16 + l15) * 64 + pc * 8];
        for (int qs = 0; qs < 2; qs++) {
          s0[qs] = __builtin_amdgcn_mfma_f32_16x16x32_bf16(k0f, qf[qs][kc], s0[qs], 0, 0, 0);
          s1[qs] = __builtin_amdgcn_mfma_f32_16x16x32_bf16(k1f, qf[qs][kc], s1[qs], 0, 0, 0);
        }
      }
      for (int qs = 0; qs < 2; qs++) {
        i32x4 d;
        d[0] = (int)pk2t(e2(s0[qs][0]), e2(s0[qs][1]));
        d[1] = (int)pk2t(e2(s0[qs][2]), e2(s0[qs][3]));
        d[2] = (int)pk2t(e2(s1[qs][0]), e2(s1[qs][1]));
        d[3] = (int)pk2t(e2(s1[qs][2]), e2(s1[qs][3]));
        bfr[qs][c] = __builtin_bit_cast(s16x8, d);
      }
    }

    for (int c = 0; c < 2; c++) {
      lacc[0] = __builtin_amdgcn_mfma_f32_16x16x32_bf16(ones, bfr[0][c], lacc[0], 0, 0, 0);
      lacc[1] = __builtin_amdgcn_mfma_f32_16x16x32_bf16(ones, bfr[1][c], lacc[1], 0, 0, 0);
      for (int et = 0; et < 4; et++) {
        int pc = (c * 4 + quad) ^ (l15 & 7);
        s16x8 vf = *(const s16x8*)&vsb[(et * 16 + l15) * 64 + pc * 8];
        o[0][et] = __builtin_amdgcn_mfma_f32_16x16x32_bf16(vf, bfr[0][c], o[0][et], 0, 0, 0);
        o[1][et] = __builtin_amdgcn_mfma_f32_16x16x32_bf16(vf, bfr[1][c], o[1][et], 0, 0, 0);
      }
    }

    // counted drain: retire tile kt+1 (issued one full compute phase ago), keep
    // tile kt+2 in flight across the barrier. Tail: kt==30 drains tile 31 fully.
    if (kt < 30)       __builtin_amdgcn_s_waitcnt(0x0F74);  // vmcnt(4)
    else if (kt == 30) __builtin_amdgcn_s_waitcnt(0x0F70);  // vmcnt(0)
    if (kt < 31) {
      __builtin_amdgcn_s_barrier();
      __builtin_amdgcn_sched_barrier(0);
    }
    int nc = cur + 1; cur = (nc == 3) ? 0 : nc;
    int np = pre + 1; pre = (np == 3) ? 0 : np;
  }
#undef STAGE

  int bb = bh >> 3;
  for (int half = 0; half < 2; half++) {
    __syncthreads();
    if ((wave >> 1) == half) {
      int tl = (wave & 1) * 32;
      for (int qs = 0; qs < 2; qs++) {
        int row = tl + qs * 16 + l15;
        if (quad == 0) sm.ep.linv[row] = 1.f / lacc[qs][0];
        for (int et = 0; et < 4; et++)
          for (int r = 0; r < 4; r++)
            sm.ep.ows[row * 65 + et * 16 + quad * 4 + r] = o[qs][et][r];
      }
    }
    __syncthreads();
    for (int i = 0; i < 16; i++) {
      int row = wave * 16 + i;
      int gt = qt * 128 + half * 64 + row;
      float val = sm.ep.ows[row * 65 + lane] * sm.ep.linv[row] * wgl;
      atomicAdd(&out[(((size_t)bb * T_ + gt) << 6) + lane], val);
    }
  }
}

extern "C" void kernel_launch(void* const* d_in, const int* in_sizes, int n_in,
                              void* d_out, int out_size, void* d_ws, size_t ws_size,
                              hipStream_t stream) {
  const float* obs = (const float*)d_in[0];
  const float* st  = (const float*)d_in[1];
  const float* Wq  = (const float*)d_in[2];
  const float* Wk  = (const float*)d_in[3];
  const float* Wv  = (const float*)d_in[4];
  const float* mw  = (const float*)d_in[5];

  const size_t WS_NEEDED = 27262976;   // proven 26 MB layout
  const size_t WS_BIG    = 44040192;   // +16 MB bf16 activations
  char* ws = (char*)d_ws;
  ushort_t* wt  = (ushort_t*)ws;                     // 1.5 MB
  float*    wgt = (float*)(ws + 1572864u);           // 2 KB
  ushort_t* qo  = (ushort_t*)(ws + 2097152u);        // [B,H,T,E] bf16, 8 MB
  ushort_t* ko  = (ushort_t*)(ws + 10485760u);       // [B,H,T,E] bf16, 8 MB
  ushort_t* vto = (ushort_t*)(ws + 18874368u);       // [B,H,E,T] bf16, 8 MB
  ushort_t* xo  = (ushort_t*)(ws + 27262976u);       // obs bf16, 8 MB
  ushort_t* xs  = (ushort_t*)(ws + 35651584u);       // st  bf16, 8 MB
  float*    out = (float*)d_out;

  hipMemsetAsync(d_out, 0, (size_t)out_size * sizeof(float), stream);
  if (ws_size < WS_NEEDED) return;

  hipLaunchKernelGGL(k_prep, dim3(8, 8, 3), dim3(256), 0, stream, Wq, Wk, Wv, wt);
  hipLaunchKernelGGL(k_wgt,  dim3(1),       dim3(64),  0, stream, mw, wgt);
  if (ws_size >= WS_BIG) {
    hipLaunchKernelGGL(k_cvt,   dim3(2048, 2), dim3(256), 0, stream, obs, st,
                       (unsigned*)xo, (unsigned*)xs);
    hipLaunchKernelGGL(k_proj2, dim3(768),     dim3(256), 0, stream, xo, xs, wt, qo, ko, vto);
  } else {
    hipLaunchKernelGGL(k_proj,  dim3(768),     dim3(256), 0, stream, obs, st, wt, qo, ko, vto);
  }
  hipLaunchKernelGGL(k_attn, dim3(512), dim3(256), 0, stream, qo, ko, vto, wgt, out);
}